// Round 1
// baseline (445.768 us; speedup 1.0000x reference)
//
#include <hip/hip_runtime.h>
#include <math.h>

// Problem constants from the reference: B=4096, K=64, D=128.
// D=128 floats = 32 float4 per embedding row; one 32-lane half-wave gathers
// a full row with a single coalesced dwordx4 load (512 B).

__device__ __forceinline__ float halfwave_sum(float v) {
    // Reduce across the 32-lane half-wave. xor offsets 1..16 never cross the
    // 32-lane halves of the wave64, so lanes [0,32) and [32,64) reduce
    // independently (they hold different k rows).
    #pragma unroll
    for (int off = 16; off; off >>= 1) v += __shfl_xor(v, off);
    return v;
}

__global__ __launch_bounds__(256) void cml_dist_kernel(
    const int* __restrict__ pairs,     // (B,2)
    const int* __restrict__ pos_art,   // (B,)
    const int* __restrict__ pos_alb,   // (B,)
    const int* __restrict__ neg_samp,  // (B,K)
    const int* __restrict__ neg_art,   // (B,K)
    const int* __restrict__ neg_alb,   // (B,K)
    const float4* __restrict__ Wu,     // (N_USERS, 32) as float4
    const float4* __restrict__ Wi,     // (N_ITEMS, 32)
    const float4* __restrict__ Wart,   // (N_ARTISTS, 32)
    const float4* __restrict__ Walb,   // (N_ALBUMS, 32)
    float* __restrict__ out_pos,       // (B,)
    float* __restrict__ out_dist,      // (B,K)
    float* __restrict__ out_min,       // (B,)
    int Kn)
{
    const int b    = blockIdx.x;
    const int tid  = threadIdx.x;
    const int lane = tid & 31;   // lane within half-wave
    const int hw   = tid >> 5;   // half-wave id, 0..7

    __shared__ float s_dist[64]; // K == 64

    // User vector: lane l holds float4 element l (elements 4l..4l+3).
    const int u_idx = pairs[2 * b];
    const float4 u = Wu[(size_t)u_idx * 32 + lane];

    const float inv3 = 1.0f / 3.0f;

    // Positive distance: half-wave 0 only (one extra row-triple per block).
    if (hw == 0) {
        const int ii = pairs[2 * b + 1];
        const int ia = pos_art[b];
        const int il = pos_alb[b];
        const float4 a = Wi  [(size_t)ii * 32 + lane];
        const float4 r = Wart[(size_t)ia * 32 + lane];
        const float4 l = Walb[(size_t)il * 32 + lane];
        const float dx = u.x - (a.x + r.x + l.x) * inv3;
        const float dy = u.y - (a.y + r.y + l.y) * inv3;
        const float dz = u.z - (a.z + r.z + l.z) * inv3;
        const float dw = u.w - (a.w + r.w + l.w) * inv3;
        float acc = dx * dx + dy * dy + dz * dz + dw * dw;
        acc = halfwave_sum(acc);
        if (lane == 0) out_pos[b] = acc;
    }

    // Negative distances: each half-wave handles k = hw, hw+8, ..., hw+56.
    for (int kk = hw; kk < Kn; kk += 8) {
        const int base = b * Kn + kk;
        const int ii = neg_samp[base];
        const int ia = neg_art [base];
        const int il = neg_alb [base];
        const float4 a = Wi  [(size_t)ii * 32 + lane];
        const float4 r = Wart[(size_t)ia * 32 + lane];
        const float4 l = Walb[(size_t)il * 32 + lane];
        const float dx = u.x - (a.x + r.x + l.x) * inv3;
        const float dy = u.y - (a.y + r.y + l.y) * inv3;
        const float dz = u.z - (a.z + r.z + l.z) * inv3;
        const float dw = u.w - (a.w + r.w + l.w) * inv3;
        float acc = dx * dx + dy * dy + dz * dz + dw * dw;
        acc = halfwave_sum(acc);
        if (lane == 0) {
            out_dist[base] = acc;
            s_dist[kk]     = acc;
        }
    }

    __syncthreads();

    // Min over the K=64 negative distances: first wave (tid < 64) does a
    // wave64 shuffle-min.
    if (tid < 64) {
        float v = (tid < Kn) ? s_dist[tid] : INFINITY;
        #pragma unroll
        for (int off = 32; off; off >>= 1) {
            const float o = __shfl_down(v, off, 64);
            v = fminf(v, o);
        }
        if (tid == 0) out_min[b] = v;
    }
}

extern "C" void kernel_launch(void* const* d_in, const int* in_sizes, int n_in,
                              void* d_out, int out_size, void* d_ws, size_t ws_size,
                              hipStream_t stream) {
    const int* pairs    = (const int*)d_in[0];
    const int* pos_art  = (const int*)d_in[1];
    const int* pos_alb  = (const int*)d_in[2];
    const int* neg_samp = (const int*)d_in[3];
    const int* neg_art  = (const int*)d_in[4];
    const int* neg_alb  = (const int*)d_in[5];
    // d_in[6] titles, d_in[7] titles_len: unused by the reference math.
    const float4* Wu   = (const float4*)d_in[8];
    const float4* Wi   = (const float4*)d_in[9];
    const float4* Wart = (const float4*)d_in[10];
    const float4* Walb = (const float4*)d_in[11];

    const int Bn = in_sizes[1];            // 4096
    const int Kn = in_sizes[3] / Bn;       // 64

    float* out      = (float*)d_out;
    float* out_pos  = out;                         // (B,)
    float* out_dist = out + Bn;                    // (B,K)
    float* out_min  = out + Bn + (size_t)Bn * Kn;  // (B,)

    cml_dist_kernel<<<Bn, 256, 0, stream>>>(
        pairs, pos_art, pos_alb, neg_samp, neg_art, neg_alb,
        Wu, Wi, Wart, Walb, out_pos, out_dist, out_min, Kn);
}